// Round 6
// baseline (327.147 us; speedup 1.0000x reference)
//
#include <hip/hip_runtime.h>
#include <hip/hip_bf16.h>
#include <hip/hip_fp16.h>
#include <math.h>

constexpr int NN = 50000;
constexpr int EE = 800000;
constexpr int SCAN_NB = (NN + 255) / 256;   // 196

typedef short v8s __attribute__((ext_vector_type(8)));
typedef float v4f __attribute__((ext_vector_type(4)));

__device__ __forceinline__ short f2b(float f){
  __hip_bfloat16 h = __float2bfloat16(f);
  return *reinterpret_cast<short*>(&h);
}
__device__ __forceinline__ __half2 u2h2(unsigned int u){
  union { unsigned int u; __half2 h; } c; c.u = u; return c.h;
}

__global__ void hist_kernel(const int* __restrict__ ei, int* __restrict__ deg){
  int e = blockIdx.x * blockDim.x + threadIdx.x;
  if (e < EE) atomicAdd(&deg[ei[EE + e]], 1);
}

// --- 3-phase parallel exclusive scan of deg[NN] ---
__global__ __launch_bounds__(256) void partial_sum_kernel(const int* __restrict__ deg,
                                                          int* __restrict__ psum){
  int b = blockIdx.x, tid = threadIdx.x, lane = tid & 63, wv = tid >> 6;
  int i = b * 256 + tid;
  int v = (i < NN) ? deg[i] : 0;
  #pragma unroll
  for (int m = 1; m < 64; m <<= 1) v += __shfl_xor(v, m);
  __shared__ int ws[4];
  if (lane == 0) ws[wv] = v;
  __syncthreads();
  if (tid == 0) psum[b] = ws[0] + ws[1] + ws[2] + ws[3];
}

__global__ __launch_bounds__(256) void scan_partials_kernel(int* __restrict__ psum){
  int tid = threadIdx.x, lane = tid & 63, wv = tid >> 6;
  int own = (tid < SCAN_NB) ? psum[tid] : 0;
  int v = own;
  #pragma unroll
  for (int off = 1; off < 64; off <<= 1){
    int t = __shfl_up(v, off);
    if (lane >= off) v += t;
  }
  __shared__ int ws[4];
  if (lane == 63) ws[wv] = v;
  __syncthreads();
  int add = 0;
  #pragma unroll
  for (int w = 0; w < 4; w++) if (w < wv) add += ws[w];
  if (tid < SCAN_NB) psum[tid] = v + add - own;     // exclusive
}

__global__ __launch_bounds__(256) void final_scan_kernel(const int* __restrict__ deg,
                                                         const int* __restrict__ psum,
                                                         int* __restrict__ row_ptr,
                                                         int* __restrict__ cursor){
  int b = blockIdx.x, tid = threadIdx.x, lane = tid & 63, wv = tid >> 6;
  int i = b * 256 + tid;
  int d = (i < NN) ? deg[i] : 0;
  int v = d;
  #pragma unroll
  for (int off = 1; off < 64; off <<= 1){
    int t = __shfl_up(v, off);
    if (lane >= off) v += t;
  }
  __shared__ int ws[4];
  if (lane == 63) ws[wv] = v;
  __syncthreads();
  int add = psum[b];
  #pragma unroll
  for (int w = 0; w < 4; w++) if (w < wv) add += ws[w];
  if (i < NN){
    row_ptr[i + 1] = add + v;
    cursor[i]      = add + v - d;
  }
  if (i == 0) row_ptr[0] = 0;
}

__global__ void fill_kernel(const int* __restrict__ ei, int* __restrict__ cursor,
                            int* __restrict__ col_src){
  int e = blockIdx.x * blockDim.x + threadIdx.x;
  if (e < EE){
    int src = ei[e], dst = ei[EE + e];
    int pos = atomicAdd(&cursor[dst], 1);
    col_src[pos] = src;
  }
}

// pack 4 weight matrices (each [96][K] f32) + biases into bf16 Wcat[384][K], f32 bcat[384]
__global__ void pack_kernel(const float* __restrict__ Wq, const float* __restrict__ bq,
                            const float* __restrict__ Wk, const float* __restrict__ bk,
                            const float* __restrict__ Wv, const float* __restrict__ bv,
                            const float* __restrict__ Ws, const float* __restrict__ bs,
                            short* __restrict__ Wcat, float* __restrict__ bcat, int K){
  int c = blockIdx.x;            // 0..383
  int which = c / 96, r = c % 96;
  const float* Wsel = which == 0 ? Wq : which == 1 ? Wk : which == 2 ? Wv : Ws;
  const float* bsel = which == 0 ? bq : which == 1 ? bk : which == 2 ? bv : bs;
  for (int k = threadIdx.x; k < K; k += blockDim.x)
    Wcat[(size_t)c * K + k] = f2b(Wsel[(size_t)r * K + k]);
  if (threadIdx.x == 0) bcat[c] = bsel[r];
}

// C[M][384] = A[M][K] @ Wcat[384][K](bf16)^T + bcat, via mfma_f32_16x16x32_bf16.
// 256x128 tile, 8 waves 4x2 (512 thr). Whole K staged in LDS once.
template<int K, bool AF32>
__global__ __launch_bounds__(512) void gemm_kernel(const void* __restrict__ Ain,
                                                   const short* __restrict__ Wcat,
                                                   const float* __restrict__ bcat,
                                                   float* __restrict__ qs,
                                                   __half* __restrict__ kvb,
                                                   int M){
  constexpr int KP = K + 8;              // +16B pad: fragment reads alias only 2-way
  constexpr int UNITS = K / 8;           // 8-elem units per row
  __shared__ __attribute__((aligned(16))) short As[256 * KP];
  __shared__ __attribute__((aligned(16))) short Bs[128 * KP];
  const int tid = threadIdx.x;
  const int rt = blockIdx.x * 256, ct = blockIdx.y * 128;

  #pragma unroll
  for (int it = 0; it < (256 * UNITS) / 512; ++it){
    int li = it * 512 + tid;
    int row = li / UNITS, u = li % UNITS;
    int grow = min(rt + row, M - 1);
    if constexpr (AF32){
      const float* A = (const float*)Ain;
      float4 a0 = *(const float4*)(A + (size_t)grow * K + u * 8);
      float4 a1 = *(const float4*)(A + (size_t)grow * K + u * 8 + 4);
      v8s o;
      o[0] = f2b(a0.x); o[1] = f2b(a0.y); o[2] = f2b(a0.z); o[3] = f2b(a0.w);
      o[4] = f2b(a1.x); o[5] = f2b(a1.y); o[6] = f2b(a1.z); o[7] = f2b(a1.w);
      *(v8s*)&As[row * KP + u * 8] = o;
    } else {
      const short* A = (const short*)Ain;
      *(v8s*)&As[row * KP + u * 8] = *(const v8s*)(A + (size_t)grow * K + u * 8);
    }
  }
  #pragma unroll
  for (int it = 0; it < (128 * UNITS) / 512; ++it){
    int li = it * 512 + tid;
    int row = li / UNITS, u = li % UNITS;
    int gcol = ct + row;                 // < 384 always
    *(v8s*)&Bs[row * KP + u * 8] = *(const v8s*)(Wcat + (size_t)gcol * K + u * 8);
  }
  __syncthreads();

  const int lane = tid & 63;
  const int wid  = tid >> 6;
  const int wm = wid >> 1, wn = wid & 1;
  const int fr = lane & 15, fk = lane >> 4;

  v4f acc[4][4];
  #pragma unroll
  for (int i = 0; i < 4; i++)
    #pragma unroll
    for (int j = 0; j < 4; j++) acc[i][j] = (v4f){0.f, 0.f, 0.f, 0.f};

  #pragma unroll
  for (int ks = 0; ks < K / 32; ++ks){
    const int kofs = ks * 32 + fk * 8;
    v8s a[4], b[4];
    #pragma unroll
    for (int i = 0; i < 4; i++)
      a[i] = *(const v8s*)&As[(wm * 64 + i * 16 + fr) * KP + kofs];
    #pragma unroll
    for (int j = 0; j < 4; j++)
      b[j] = *(const v8s*)&Bs[(wn * 64 + j * 16 + fr) * KP + kofs];
    #pragma unroll
    for (int i = 0; i < 4; i++)
      #pragma unroll
      for (int j = 0; j < 4; j++)
        acc[i][j] = __builtin_amdgcn_mfma_f32_16x16x32_bf16(a[i], b[j], acc[i][j], 0, 0, 0);
  }

  #pragma unroll
  for (int i = 0; i < 4; i++){
    #pragma unroll
    for (int j = 0; j < 4; j++){
      const int gcol = ct + wn * 64 + j * 16 + fr;
      const float bias = bcat[gcol];
      #pragma unroll
      for (int r = 0; r < 4; r++){
        const int grow = rt + wm * 64 + i * 16 + fk * 4 + r;
        if (grow < M){
          float val = acc[i][j][r] + bias;
          if (gcol < 96)       qs[(size_t)grow * 192 + gcol] = val;
          else if (gcol < 192) kvb[(size_t)grow * 192 + (gcol - 96)] = __float2half(val);
          else if (gcol < 288) kvb[(size_t)grow * 192 + 96 + (gcol - 192)] = __float2half(val);
          else                 qs[(size_t)grow * 192 + 96 + (gcol - 288)] = val;
        }
      }
    }
  }
}

// persistent waves, one node per wave iteration; 64-edge windows, 16-edge chunks.
// window: one coalesced col_src load (64 lanes); chunks 2-deep software-pipelined
// (k/v gathers for chunk c+1 issued before chunk c is consumed). f16 k/v, packed hfma2.
__global__ __launch_bounds__(256) void attn_kernel(
    const float* __restrict__ qs, const __half* __restrict__ kv,
    const int* __restrict__ row_ptr, const int* __restrict__ col_src,
    const float* __restrict__ Wb, const float* __restrict__ gamma,
    const float* __restrict__ beta, float* __restrict__ outp,
    short* __restrict__ h1b, int mode){
  const int lane = threadIdx.x & 63;
  const int wid  = threadIdx.x >> 6;
  const int gw   = blockIdx.x * 4 + wid;
  const int nw   = gridDim.x * 4;
  const int h_a = lane & 3;
  const int g_a = lane >> 2;
  const int l_v = lane & 15;
  const int vg  = lane >> 4;
  const int h_v = l_v >> 2;
  const char* kvc = (const char*)kv;

  for (int n = gw; n < NN; n += nw){
    __half2 qh[12];
    {
      const float* qrow = qs + (size_t)n * 192 + h_a * 24;
      #pragma unroll
      for (int i = 0; i < 12; i++)
        qh[i] = __floats2half2_rn(qrow[2 * i], qrow[2 * i + 1]);
    }
    const int rs = row_ptr[n], re = row_ptr[n + 1];
    float m = -INFINITY, s = 0.f;
    float acc[6] = {0.f, 0.f, 0.f, 0.f, 0.f, 0.f};

    for (int wb = rs; wb < re; wb += 64){
      const int wn = min(64, re - wb);
      const int srcs = col_src[wb + min(lane, wn - 1)];
      const int nch = (wn + 15) >> 4;
      uint4 K0[3], K1[3];
      unsigned V0[4][3], V1[4][3];

      auto LOADC = [&](int c, uint4* K, unsigned (*V)[3]){
        int ea = min(16 * c + g_a, wn - 1);
        int sa = __shfl(srcs, ea);
        unsigned ko = (unsigned)sa * 384u + (unsigned)(h_a * 48);
        const uint4* kp = (const uint4*)(kvc + ko);
        K[0] = kp[0]; K[1] = kp[1]; K[2] = kp[2];
        #pragma unroll
        for (int st = 0; st < 4; st++){
          int ev = min(16 * c + st * 4 + vg, wn - 1);
          int sv = __shfl(srcs, ev);
          unsigned vo = (unsigned)sv * 384u + 192u + (unsigned)(12 * l_v);
          const unsigned* vp = (const unsigned*)(kvc + vo);
          V[st][0] = vp[0]; V[st][1] = vp[1]; V[st][2] = vp[2];
        }
      };
      auto COMPUTE = [&](int c, const uint4* K, const unsigned (*V)[3]){
        const int cnt = min(wn - 16 * c, 16);   // edges in this chunk (>=1)
        __half2 d0 = __floats2half2_rn(0.f, 0.f), d1 = d0;
        d0 = __hfma2(qh[0],  u2h2(K[0].x), d0); d1 = __hfma2(qh[1],  u2h2(K[0].y), d1);
        d0 = __hfma2(qh[2],  u2h2(K[0].z), d0); d1 = __hfma2(qh[3],  u2h2(K[0].w), d1);
        d0 = __hfma2(qh[4],  u2h2(K[1].x), d0); d1 = __hfma2(qh[5],  u2h2(K[1].y), d1);
        d0 = __hfma2(qh[6],  u2h2(K[1].z), d0); d1 = __hfma2(qh[7],  u2h2(K[1].w), d1);
        d0 = __hfma2(qh[8],  u2h2(K[2].x), d0); d1 = __hfma2(qh[9],  u2h2(K[2].y), d1);
        d0 = __hfma2(qh[10], u2h2(K[2].z), d0); d1 = __hfma2(qh[11], u2h2(K[2].w), d1);
        float dot = __low2float(d0) + __high2float(d0) + __low2float(d1) + __high2float(d1);
        float al = (g_a < cnt) ? dot * 0.2041241452319315f : -INFINITY;
        float cm = al;
        cm = fmaxf(cm, __shfl_xor(cm, 4));
        cm = fmaxf(cm, __shfl_xor(cm, 8));
        cm = fmaxf(cm, __shfl_xor(cm, 16));
        cm = fmaxf(cm, __shfl_xor(cm, 32));
        float nm = fmaxf(m, cm);
        float r  = __expf(m - nm);          // first chunk: 0
        float e  = __expf(al - nm);         // padded lanes: 0
        float cs = e;
        cs += __shfl_xor(cs, 4);
        cs += __shfl_xor(cs, 8);
        cs += __shfl_xor(cs, 16);
        cs += __shfl_xor(cs, 32);
        s = s * r + cs;
        m = nm;
        float rv = __shfl(r, h_v);
        __half2 ch0 = __floats2half2_rn(0.f, 0.f), ch1 = ch0, ch2 = ch0;
        #pragma unroll
        for (int st = 0; st < 4; st++){
          float w = __shfl(e, 4 * (st * 4 + vg) + h_v);   // padded edges: e==0
          __half2 w2 = __float2half2_rn(w);
          ch0 = __hfma2(w2, u2h2(V[st][0]), ch0);
          ch1 = __hfma2(w2, u2h2(V[st][1]), ch1);
          ch2 = __hfma2(w2, u2h2(V[st][2]), ch2);
        }
        acc[0] = fmaf(acc[0], rv, __low2float(ch0));
        acc[1] = fmaf(acc[1], rv, __high2float(ch0));
        acc[2] = fmaf(acc[2], rv, __low2float(ch1));
        acc[3] = fmaf(acc[3], rv, __high2float(ch1));
        acc[4] = fmaf(acc[4], rv, __low2float(ch2));
        acc[5] = fmaf(acc[5], rv, __high2float(ch2));
      };

      LOADC(0, K0, V0);
      int c = 0;
      while (true){
        if (c + 1 < nch) LOADC(c + 1, K1, V1);
        COMPUTE(c, K0, V0);
        if (++c >= nch) break;
        if (c + 1 < nch) LOADC(c + 1, K0, V0);
        COMPUTE(c, K1, V1);
        if (++c >= nch) break;
      }
    }

    #pragma unroll
    for (int i = 0; i < 6; i++){
      acc[i] += __shfl_xor(acc[i], 16);
      acc[i] += __shfl_xor(acc[i], 32);
    }
    float sv  = __shfl(s, h_v);
    float inv = (re > rs) ? 1.0f / sv : 0.f;
    float o[6], xr[6];
    #pragma unroll
    for (int i = 0; i < 6; i++) o[i] = acc[i] * inv;
    const float* xrp = qs + (size_t)n * 192 + 96 + 6 * l_v;
    #pragma unroll
    for (int i = 0; i < 6; i++) xr[i] = xrp[i];

    float p = 0.f;
    #pragma unroll
    for (int i = 0; i < 6; i++){
      int f = 6 * l_v + i;
      p += Wb[f] * o[i] + Wb[96 + f] * xr[i] + Wb[192 + f] * (o[i] - xr[i]);
    }
    p += __shfl_xor(p, 1);
    p += __shfl_xor(p, 2);
    p += __shfl_xor(p, 4);
    p += __shfl_xor(p, 8);
    float g = 1.0f / (1.0f + __expf(-p));
    float y[6];
    #pragma unroll
    for (int i = 0; i < 6; i++) y[i] = g * xr[i] + (1.0f - g) * o[i];

    if (mode == 0){
      #pragma unroll
      for (int i = 0; i < 6; i++)
        y[i] = 0.5f * y[i] * (1.0f + erff(y[i] * 0.7071067811865475f));
      if (vg == 0){
        short* op = h1b + (size_t)n * 96 + 6 * l_v;
        #pragma unroll
        for (int i = 0; i < 6; i++) op[i] = f2b(y[i]);
      }
    } else {
      float ssum = y[0] + y[1] + y[2] + y[3] + y[4] + y[5];
      ssum += __shfl_xor(ssum, 1);
      ssum += __shfl_xor(ssum, 2);
      ssum += __shfl_xor(ssum, 4);
      ssum += __shfl_xor(ssum, 8);
      float mu = ssum * (1.0f / 96.0f);
      float vsum = 0.f;
      #pragma unroll
      for (int i = 0; i < 6; i++){ float d = y[i] - mu; vsum += d * d; }
      vsum += __shfl_xor(vsum, 1);
      vsum += __shfl_xor(vsum, 2);
      vsum += __shfl_xor(vsum, 4);
      vsum += __shfl_xor(vsum, 8);
      float invs = rsqrtf(vsum * (1.0f / 96.0f) + 1e-5f);
      if (vg == 0){
        float* op = outp + (size_t)n * 96 + 6 * l_v;
        #pragma unroll
        for (int i = 0; i < 6; i++){
          int f = 6 * l_v + i;
          op[i] = (y[i] - mu) * invs * gamma[f] + beta[f];
        }
      }
    }
  }
}

extern "C" void kernel_launch(void* const* d_in, const int* in_sizes, int n_in,
                              void* d_out, int out_size, void* d_ws, size_t ws_size,
                              hipStream_t stream){
  const float* x    = (const float*)d_in[0];
  const int*   ei   = (const int*)d_in[1];
  const float* Wq1  = (const float*)d_in[2];
  const float* bq1  = (const float*)d_in[3];
  const float* Wk1  = (const float*)d_in[4];
  const float* bk1  = (const float*)d_in[5];
  const float* Wv1  = (const float*)d_in[6];
  const float* bv1  = (const float*)d_in[7];
  const float* Ws1  = (const float*)d_in[8];
  const float* bs1  = (const float*)d_in[9];
  const float* Wb1  = (const float*)d_in[10];
  const float* Wq2  = (const float*)d_in[11];
  const float* bq2  = (const float*)d_in[12];
  const float* Wk2  = (const float*)d_in[13];
  const float* bk2  = (const float*)d_in[14];
  const float* Wv2  = (const float*)d_in[15];
  const float* bv2  = (const float*)d_in[16];
  const float* Ws2  = (const float*)d_in[17];
  const float* bs2  = (const float*)d_in[18];
  const float* Wb2  = (const float*)d_in[19];
  const float* gamma = (const float*)d_in[20];
  const float* beta  = (const float*)d_in[21];
  float* out = (float*)d_out;

  char* ws = (char*)d_ws;
  size_t off = 0;
  auto take = [&](size_t b) -> void* {
    void* p = ws + off;
    off += (b + 255) & ~(size_t)255;
    return p;
  };
  float* qs            = (float*)take((size_t)NN * 192 * 4);
  __half* kvb          = (__half*)take((size_t)NN * 192 * 2);
  short* h1b           = (short*)take((size_t)NN * 96 * 2);
  short* Wcat          = (short*)take((size_t)384 * 128 * 2);
  float* bcat          = (float*)take(384 * 4);
  int* deg             = (int*)take((size_t)NN * 4);
  int* cursor          = (int*)take((size_t)NN * 4);
  int* row_ptr         = (int*)take((size_t)(NN + 1) * 4);
  int* col_src         = (int*)take((size_t)EE * 4);
  int* psum            = (int*)take((size_t)SCAN_NB * 4);

  // CSR build (shared by both layers)
  hipMemsetAsync(deg, 0, (size_t)NN * 4, stream);
  hist_kernel<<<(EE + 255) / 256, 256, 0, stream>>>(ei, deg);
  partial_sum_kernel<<<SCAN_NB, 256, 0, stream>>>(deg, psum);
  scan_partials_kernel<<<1, 256, 0, stream>>>(psum);
  final_scan_kernel<<<SCAN_NB, 256, 0, stream>>>(deg, psum, row_ptr, cursor);
  fill_kernel<<<(EE + 255) / 256, 256, 0, stream>>>(ei, cursor, col_src);

  dim3 gg((NN + 255) / 256, 3);
  // layer 1 (A = x f32, converted in gemm staging)
  pack_kernel<<<384, 128, 0, stream>>>(Wq1, bq1, Wk1, bk1, Wv1, bv1, Ws1, bs1, Wcat, bcat, 128);
  gemm_kernel<128, true><<<gg, 512, 0, stream>>>(x, Wcat, bcat, qs, kvb, NN);
  attn_kernel<<<2048, 256, 0, stream>>>(qs, kvb, row_ptr, col_src, Wb1,
                                        nullptr, nullptr, nullptr, h1b, 0);
  // layer 2 (A = h1b bf16)
  pack_kernel<<<384, 128, 0, stream>>>(Wq2, bq2, Wk2, bk2, Wv2, bv2, Ws2, bs2, Wcat, bcat, 96);
  gemm_kernel<96, false><<<gg, 512, 0, stream>>>(h1b, Wcat, bcat, qs, kvb, NN);
  attn_kernel<<<2048, 256, 0, stream>>>(qs, kvb, row_ptr, col_src, Wb2,
                                        gamma, beta, out, nullptr, 1);
}

// Round 7
// 283.764 us; speedup vs baseline: 1.1529x; 1.1529x over previous
//
#include <hip/hip_runtime.h>
#include <hip/hip_bf16.h>
#include <hip/hip_fp16.h>
#include <math.h>

constexpr int NN = 50000;
constexpr int EE = 800000;
constexpr int SCAN_NB = (NN + 255) / 256;   // 196

typedef short v8s __attribute__((ext_vector_type(8)));
typedef float v4f __attribute__((ext_vector_type(4)));

__device__ __forceinline__ short f2b(float f){
  __hip_bfloat16 h = __float2bfloat16(f);
  return *reinterpret_cast<short*>(&h);
}
__device__ __forceinline__ __half2 u2h2(unsigned int u){
  union { unsigned int u; __half2 h; } c; c.u = u; return c.h;
}

__global__ void hist_kernel(const int* __restrict__ ei, int* __restrict__ deg){
  int e = blockIdx.x * blockDim.x + threadIdx.x;
  if (e < EE) atomicAdd(&deg[ei[EE + e]], 1);
}

// --- 3-phase parallel exclusive scan of deg[NN] ---
__global__ __launch_bounds__(256) void partial_sum_kernel(const int* __restrict__ deg,
                                                          int* __restrict__ psum){
  int b = blockIdx.x, tid = threadIdx.x, lane = tid & 63, wv = tid >> 6;
  int i = b * 256 + tid;
  int v = (i < NN) ? deg[i] : 0;
  #pragma unroll
  for (int m = 1; m < 64; m <<= 1) v += __shfl_xor(v, m);
  __shared__ int ws[4];
  if (lane == 0) ws[wv] = v;
  __syncthreads();
  if (tid == 0) psum[b] = ws[0] + ws[1] + ws[2] + ws[3];
}

__global__ __launch_bounds__(256) void scan_partials_kernel(int* __restrict__ psum){
  int tid = threadIdx.x, lane = tid & 63, wv = tid >> 6;
  int own = (tid < SCAN_NB) ? psum[tid] : 0;
  int v = own;
  #pragma unroll
  for (int off = 1; off < 64; off <<= 1){
    int t = __shfl_up(v, off);
    if (lane >= off) v += t;
  }
  __shared__ int ws[4];
  if (lane == 63) ws[wv] = v;
  __syncthreads();
  int add = 0;
  #pragma unroll
  for (int w = 0; w < 4; w++) if (w < wv) add += ws[w];
  if (tid < SCAN_NB) psum[tid] = v + add - own;     // exclusive
}

__global__ __launch_bounds__(256) void final_scan_kernel(const int* __restrict__ deg,
                                                         const int* __restrict__ psum,
                                                         int* __restrict__ row_ptr,
                                                         int* __restrict__ cursor){
  int b = blockIdx.x, tid = threadIdx.x, lane = tid & 63, wv = tid >> 6;
  int i = b * 256 + tid;
  int d = (i < NN) ? deg[i] : 0;
  int v = d;
  #pragma unroll
  for (int off = 1; off < 64; off <<= 1){
    int t = __shfl_up(v, off);
    if (lane >= off) v += t;
  }
  __shared__ int ws[4];
  if (lane == 63) ws[wv] = v;
  __syncthreads();
  int add = psum[b];
  #pragma unroll
  for (int w = 0; w < 4; w++) if (w < wv) add += ws[w];
  if (i < NN){
    row_ptr[i + 1] = add + v;
    cursor[i]      = add + v - d;
  }
  if (i == 0) row_ptr[0] = 0;
}

__global__ void fill_kernel(const int* __restrict__ ei, int* __restrict__ cursor,
                            int* __restrict__ col_src){
  int e = blockIdx.x * blockDim.x + threadIdx.x;
  if (e < EE){
    int src = ei[e], dst = ei[EE + e];
    int pos = atomicAdd(&cursor[dst], 1);
    col_src[pos] = src;
  }
}

// pack 4 weight matrices (each [96][K] f32) + biases into bf16 Wcat[384][K], f32 bcat[384]
__global__ void pack_kernel(const float* __restrict__ Wq, const float* __restrict__ bq,
                            const float* __restrict__ Wk, const float* __restrict__ bk,
                            const float* __restrict__ Wv, const float* __restrict__ bv,
                            const float* __restrict__ Ws, const float* __restrict__ bs,
                            short* __restrict__ Wcat, float* __restrict__ bcat, int K){
  int c = blockIdx.x;            // 0..383
  int which = c / 96, r = c % 96;
  const float* Wsel = which == 0 ? Wq : which == 1 ? Wk : which == 2 ? Wv : Ws;
  const float* bsel = which == 0 ? bq : which == 1 ? bk : which == 2 ? bv : bs;
  for (int k = threadIdx.x; k < K; k += blockDim.x)
    Wcat[(size_t)c * K + k] = f2b(Wsel[(size_t)r * K + k]);
  if (threadIdx.x == 0) bcat[c] = bsel[r];
}

// C[M][384] = A[M][K] @ Wcat[384][K](bf16)^T + bcat via mfma_f32_16x16x32_bf16.
// 64-row tile, 256 thr (4 waves 2x2 -> 32x64 per wave). A staged in LDS ONCE;
// loop over 3 B-panels of 128 cols (B is 98KB, L2-resident). LDS 52KB -> 3 blocks/CU.
template<int K, bool AF32>
__global__ __launch_bounds__(256) void gemm_kernel(const void* __restrict__ Ain,
                                                   const short* __restrict__ Wcat,
                                                   const float* __restrict__ bcat,
                                                   float* __restrict__ qs,
                                                   __half* __restrict__ kvb,
                                                   int M){
  constexpr int KP = K + 8;              // +16B pad: fragment reads alias only 2-way
  constexpr int UNITS = K / 8;           // 8-elem units per row
  __shared__ __attribute__((aligned(16))) short As[64 * KP];
  __shared__ __attribute__((aligned(16))) short Bs[128 * KP];
  const int tid = threadIdx.x;
  const int rt = blockIdx.x * 64;

  #pragma unroll
  for (int it = 0; it < (64 * UNITS) / 256; ++it){
    int li = it * 256 + tid;
    int row = li / UNITS, u = li % UNITS;
    int grow = min(rt + row, M - 1);
    if constexpr (AF32){
      const float* A = (const float*)Ain;
      float4 a0 = *(const float4*)(A + (size_t)grow * K + u * 8);
      float4 a1 = *(const float4*)(A + (size_t)grow * K + u * 8 + 4);
      v8s o;
      o[0] = f2b(a0.x); o[1] = f2b(a0.y); o[2] = f2b(a0.z); o[3] = f2b(a0.w);
      o[4] = f2b(a1.x); o[5] = f2b(a1.y); o[6] = f2b(a1.z); o[7] = f2b(a1.w);
      *(v8s*)&As[row * KP + u * 8] = o;
    } else {
      const short* A = (const short*)Ain;
      *(v8s*)&As[row * KP + u * 8] = *(const v8s*)(A + (size_t)grow * K + u * 8);
    }
  }

  const int lane = tid & 63;
  const int wid  = tid >> 6;
  const int wm = wid >> 1, wn = wid & 1;
  const int fr = lane & 15, fk = lane >> 4;

  for (int p = 0; p < 3; ++p){
    __syncthreads();                     // Bs free (also covers As staging on p==0)
    #pragma unroll
    for (int it = 0; it < (128 * UNITS) / 256; ++it){
      int li = it * 256 + tid;
      int row = li / UNITS, u = li % UNITS;
      int gcol = p * 128 + row;          // < 384
      *(v8s*)&Bs[row * KP + u * 8] = *(const v8s*)(Wcat + (size_t)gcol * K + u * 8);
    }
    __syncthreads();

    v4f acc[2][4];
    #pragma unroll
    for (int i = 0; i < 2; i++)
      #pragma unroll
      for (int j = 0; j < 4; j++) acc[i][j] = (v4f){0.f, 0.f, 0.f, 0.f};

    #pragma unroll
    for (int ks = 0; ks < K / 32; ++ks){
      const int kofs = ks * 32 + fk * 8;
      v8s a[2], b[4];
      #pragma unroll
      for (int i = 0; i < 2; i++)
        a[i] = *(const v8s*)&As[(wm * 32 + i * 16 + fr) * KP + kofs];
      #pragma unroll
      for (int j = 0; j < 4; j++)
        b[j] = *(const v8s*)&Bs[(wn * 64 + j * 16 + fr) * KP + kofs];
      #pragma unroll
      for (int i = 0; i < 2; i++)
        #pragma unroll
        for (int j = 0; j < 4; j++)
          acc[i][j] = __builtin_amdgcn_mfma_f32_16x16x32_bf16(a[i], b[j], acc[i][j], 0, 0, 0);
    }

    #pragma unroll
    for (int i = 0; i < 2; i++){
      #pragma unroll
      for (int j = 0; j < 4; j++){
        const int gcol = p * 128 + wn * 64 + j * 16 + fr;
        const float bias = bcat[gcol];
        #pragma unroll
        for (int r = 0; r < 4; r++){
          const int grow = rt + wm * 32 + i * 16 + fk * 4 + r;
          if (grow < M){
            float val = acc[i][j][r] + bias;
            if (gcol < 96)       qs[(size_t)grow * 192 + gcol] = val;
            else if (gcol < 192) kvb[(size_t)grow * 192 + (gcol - 96)] = __float2half(val);
            else if (gcol < 288) kvb[(size_t)grow * 192 + 96 + (gcol - 192)] = __float2half(val);
            else                 qs[(size_t)grow * 192 + 96 + (gcol - 288)] = val;
          }
        }
      }
    }
  }
}

// one wave per node; chunk of 16 edges. kv rows are f16 (k[0:96], v[96:192]).
// alpha role: lane = 4*g + h -> edge g, head h; 4-lane group reads one 192B k-row;
//   q.k dot via packed __hfma2. V role: lane = 16*vg + l -> edges st*4+vg, features
//   6l..6l+5; srcs via __shfl from alpha lanes; v prefetched to regs; per-chunk
//   accumulation in half2, folded into f32 acc with fused rescale.  (round-5 version)
__global__ __launch_bounds__(256) void attn_kernel(
    const float* __restrict__ qs, const __half* __restrict__ kv,
    const int* __restrict__ row_ptr, const int* __restrict__ col_src,
    const float* __restrict__ Wb, const float* __restrict__ gamma,
    const float* __restrict__ beta, float* __restrict__ outp,
    short* __restrict__ h1b, int mode){
  const int lane = threadIdx.x & 63;
  const int wid  = threadIdx.x >> 6;
  const int n = blockIdx.x * 4 + wid;
  if (n >= NN) return;
  const int h_a = lane & 3;
  const int g_a = lane >> 2;
  const int l_v = lane & 15;
  const int vg  = lane >> 4;
  const int h_v = l_v >> 2;

  __half2 qh[12];
  {
    const float* qrow = qs + (size_t)n * 192 + h_a * 24;
    #pragma unroll
    for (int i = 0; i < 12; i++)
      qh[i] = __floats2half2_rn(qrow[2 * i], qrow[2 * i + 1]);
  }
  const int rs = row_ptr[n], re = row_ptr[n + 1];
  float m = -INFINITY, s = 0.f;
  float acc[6] = {0.f, 0.f, 0.f, 0.f, 0.f, 0.f};

  for (int cb = rs; cb < re; cb += 16){
    const int cn = re - cb;             // >=1
    int srcv = col_src[cb + min(g_a, cn - 1)];
    int sb[4];
    #pragma unroll
    for (int st = 0; st < 4; st++)
      sb[st] = __shfl(srcv, 4 * min(st * 4 + vg, cn - 1));
    unsigned int vd[4][3];
    #pragma unroll
    for (int st = 0; st < 4; st++){
      const unsigned int* vp =
        (const unsigned int*)((const char*)kv + (size_t)sb[st] * 384 + 192 + 12 * l_v);
      vd[st][0] = vp[0]; vd[st][1] = vp[1]; vd[st][2] = vp[2];
    }
    const uint4* kp = (const uint4*)((const char*)kv + (size_t)srcv * 384 + h_a * 48);
    uint4 u0 = kp[0], u1 = kp[1], u2 = kp[2];
    __half2 d0 = __floats2half2_rn(0.f, 0.f), d1 = d0;
    d0 = __hfma2(qh[0],  u2h2(u0.x), d0); d1 = __hfma2(qh[1],  u2h2(u0.y), d1);
    d0 = __hfma2(qh[2],  u2h2(u0.z), d0); d1 = __hfma2(qh[3],  u2h2(u0.w), d1);
    d0 = __hfma2(qh[4],  u2h2(u1.x), d0); d1 = __hfma2(qh[5],  u2h2(u1.y), d1);
    d0 = __hfma2(qh[6],  u2h2(u1.z), d0); d1 = __hfma2(qh[7],  u2h2(u1.w), d1);
    d0 = __hfma2(qh[8],  u2h2(u2.x), d0); d1 = __hfma2(qh[9],  u2h2(u2.y), d1);
    d0 = __hfma2(qh[10], u2h2(u2.z), d0); d1 = __hfma2(qh[11], u2h2(u2.w), d1);
    float dot = __low2float(d0) + __high2float(d0) + __low2float(d1) + __high2float(d1);
    float al = (g_a < cn) ? dot * 0.2041241452319315f : -INFINITY;

    float cm = al;
    cm = fmaxf(cm, __shfl_xor(cm, 4));
    cm = fmaxf(cm, __shfl_xor(cm, 8));
    cm = fmaxf(cm, __shfl_xor(cm, 16));
    cm = fmaxf(cm, __shfl_xor(cm, 32));
    float nm = fmaxf(m, cm);
    float r  = __expf(m - nm);          // first chunk: 0
    float e  = __expf(al - nm);         // padded lanes: 0
    float cs = e;
    cs += __shfl_xor(cs, 4);
    cs += __shfl_xor(cs, 8);
    cs += __shfl_xor(cs, 16);
    cs += __shfl_xor(cs, 32);
    s = s * r + cs;
    m = nm;

    float rv = __shfl(r, h_v);
    __half2 ch0 = __floats2half2_rn(0.f, 0.f), ch1 = ch0, ch2 = ch0;
    #pragma unroll
    for (int st = 0; st < 4; st++){
      int eidx = st * 4 + vg;
      float w = __shfl(e, 4 * min(eidx, cn - 1) + h_v);
      if (eidx >= cn) w = 0.f;
      __half2 w2 = __float2half2_rn(w);
      ch0 = __hfma2(w2, u2h2(vd[st][0]), ch0);
      ch1 = __hfma2(w2, u2h2(vd[st][1]), ch1);
      ch2 = __hfma2(w2, u2h2(vd[st][2]), ch2);
    }
    acc[0] = fmaf(acc[0], rv, __low2float(ch0));
    acc[1] = fmaf(acc[1], rv, __high2float(ch0));
    acc[2] = fmaf(acc[2], rv, __low2float(ch1));
    acc[3] = fmaf(acc[3], rv, __high2float(ch1));
    acc[4] = fmaf(acc[4], rv, __low2float(ch2));
    acc[5] = fmaf(acc[5], rv, __high2float(ch2));
  }

  #pragma unroll
  for (int i = 0; i < 6; i++){
    acc[i] += __shfl_xor(acc[i], 16);
    acc[i] += __shfl_xor(acc[i], 32);
  }
  float sv  = __shfl(s, h_v);
  float inv = (re > rs) ? 1.0f / sv : 0.f;
  float o[6], xr[6];
  #pragma unroll
  for (int i = 0; i < 6; i++) o[i] = acc[i] * inv;
  const float* xrp = qs + (size_t)n * 192 + 96 + 6 * l_v;
  #pragma unroll
  for (int i = 0; i < 6; i++) xr[i] = xrp[i];

  float p = 0.f;
  #pragma unroll
  for (int i = 0; i < 6; i++){
    int f = 6 * l_v + i;
    p += Wb[f] * o[i] + Wb[96 + f] * xr[i] + Wb[192 + f] * (o[i] - xr[i]);
  }
  p += __shfl_xor(p, 1);
  p += __shfl_xor(p, 2);
  p += __shfl_xor(p, 4);
  p += __shfl_xor(p, 8);
  float g = 1.0f / (1.0f + __expf(-p));
  float y[6];
  #pragma unroll
  for (int i = 0; i < 6; i++) y[i] = g * xr[i] + (1.0f - g) * o[i];

  if (mode == 0){
    #pragma unroll
    for (int i = 0; i < 6; i++)
      y[i] = 0.5f * y[i] * (1.0f + erff(y[i] * 0.7071067811865475f));
    if (vg == 0){
      short* op = h1b + (size_t)n * 96 + 6 * l_v;
      #pragma unroll
      for (int i = 0; i < 6; i++) op[i] = f2b(y[i]);
    }
  } else {
    float ssum = y[0] + y[1] + y[2] + y[3] + y[4] + y[5];
    ssum += __shfl_xor(ssum, 1);
    ssum += __shfl_xor(ssum, 2);
    ssum += __shfl_xor(ssum, 4);
    ssum += __shfl_xor(ssum, 8);
    float mu = ssum * (1.0f / 96.0f);
    float vsum = 0.f;
    #pragma unroll
    for (int i = 0; i < 6; i++){ float d = y[i] - mu; vsum += d * d; }
    vsum += __shfl_xor(vsum, 1);
    vsum += __shfl_xor(vsum, 2);
    vsum += __shfl_xor(vsum, 4);
    vsum += __shfl_xor(vsum, 8);
    float invs = rsqrtf(vsum * (1.0f / 96.0f) + 1e-5f);
    if (vg == 0){
      float* op = outp + (size_t)n * 96 + 6 * l_v;
      #pragma unroll
      for (int i = 0; i < 6; i++){
        int f = 6 * l_v + i;
        op[i] = (y[i] - mu) * invs * gamma[f] + beta[f];
      }
    }
  }
}

extern "C" void kernel_launch(void* const* d_in, const int* in_sizes, int n_in,
                              void* d_out, int out_size, void* d_ws, size_t ws_size,
                              hipStream_t stream){
  const float* x    = (const float*)d_in[0];
  const int*   ei   = (const int*)d_in[1];
  const float* Wq1  = (const float*)d_in[2];
  const float* bq1  = (const float*)d_in[3];
  const float* Wk1  = (const float*)d_in[4];
  const float* bk1  = (const float*)d_in[5];
  const float* Wv1  = (const float*)d_in[6];
  const float* bv1  = (const float*)d_in[7];
  const float* Ws1  = (const float*)d_in[8];
  const float* bs1  = (const float*)d_in[9];
  const float* Wb1  = (const float*)d_in[10];
  const float* Wq2  = (const float*)d_in[11];
  const float* bq2  = (const float*)d_in[12];
  const float* Wk2  = (const float*)d_in[13];
  const float* bk2  = (const float*)d_in[14];
  const float* Wv2  = (const float*)d_in[15];
  const float* bv2  = (const float*)d_in[16];
  const float* Ws2  = (const float*)d_in[17];
  const float* bs2  = (const float*)d_in[18];
  const float* Wb2  = (const float*)d_in[19];
  const float* gamma = (const float*)d_in[20];
  const float* beta  = (const float*)d_in[21];
  float* out = (float*)d_out;

  char* ws = (char*)d_ws;
  size_t off = 0;
  auto take = [&](size_t b) -> void* {
    void* p = ws + off;
    off += (b + 255) & ~(size_t)255;
    return p;
  };
  float* qs            = (float*)take((size_t)NN * 192 * 4);
  __half* kvb          = (__half*)take((size_t)NN * 192 * 2);
  short* h1b           = (short*)take((size_t)NN * 96 * 2);
  short* Wcat          = (short*)take((size_t)384 * 128 * 2);
  float* bcat          = (float*)take(384 * 4);
  int* deg             = (int*)take((size_t)NN * 4);
  int* cursor          = (int*)take((size_t)NN * 4);
  int* row_ptr         = (int*)take((size_t)(NN + 1) * 4);
  int* col_src         = (int*)take((size_t)EE * 4);
  int* psum            = (int*)take((size_t)SCAN_NB * 4);

  // CSR build (shared by both layers)
  hipMemsetAsync(deg, 0, (size_t)NN * 4, stream);
  hist_kernel<<<(EE + 255) / 256, 256, 0, stream>>>(ei, deg);
  partial_sum_kernel<<<SCAN_NB, 256, 0, stream>>>(deg, psum);
  scan_partials_kernel<<<1, 256, 0, stream>>>(psum);
  final_scan_kernel<<<SCAN_NB, 256, 0, stream>>>(deg, psum, row_ptr, cursor);
  fill_kernel<<<(EE + 255) / 256, 256, 0, stream>>>(ei, cursor, col_src);

  const int gemm_grid = (NN + 63) / 64;   // 782
  // layer 1 (A = x f32, converted in gemm staging)
  pack_kernel<<<384, 128, 0, stream>>>(Wq1, bq1, Wk1, bk1, Wv1, bv1, Ws1, bs1, Wcat, bcat, 128);
  gemm_kernel<128, true><<<gemm_grid, 256, 0, stream>>>(x, Wcat, bcat, qs, kvb, NN);
  attn_kernel<<<(NN + 3) / 4, 256, 0, stream>>>(qs, kvb, row_ptr, col_src, Wb1,
                                                nullptr, nullptr, nullptr, h1b, 0);
  // layer 2 (A = h1b bf16)
  pack_kernel<<<384, 128, 0, stream>>>(Wq2, bq2, Wk2, bk2, Wv2, bv2, Ws2, bs2, Wcat, bcat, 96);
  gemm_kernel<96, false><<<gemm_grid, 256, 0, stream>>>(h1b, Wcat, bcat, qs, kvb, NN);
  attn_kernel<<<(NN + 3) / 4, 256, 0, stream>>>(qs, kvb, row_ptr, col_src, Wb2,
                                                gamma, beta, out, nullptr, 1);
}